// Round 1
// baseline (332.147 us; speedup 1.0000x reference)
//
#include <hip/hip_runtime.h>

// QPChargeNormalization: per batch row b (n = 8192 = 4096 iso + 4096 aniso):
//   u/2 = (sum(charge[b]) - q.c) / (q.q);  x = c + (u/2) q
//
// v2 structure: one 512-thread block per row. Per-thread payload is
// 8 float4 (2 c-iso, 2 c-aniso, 2 q-iso, 2 q-aniso) = 32 VGPRs, pinned in
// registers via an empty asm so the epilogue does ZERO global re-reads
// (the previous 256-thread/44-VGPR binary had its payload loads sunk into
// the epilogue by the register allocator -> inputs were read twice).
// __launch_bounds__(512,8) caps VGPRs at 64 -> 8 waves/SIMD, 4 blocks/CU.
// Output stores are non-temporal so the 128 MB write stream doesn't evict
// the (L3-resident) inputs between iterations.

#define HALF_N 4096   // floats per row in each of the iso/aniso halves
#define BLOCK  512

typedef float f4 __attribute__((ext_vector_type(4)));

__global__ __launch_bounds__(BLOCK, 8) void qp_charge_norm_kernel(
    const float* __restrict__ c_iso,
    const float* __restrict__ c_aniso,
    const float* __restrict__ q_iso,
    const float* __restrict__ q_aniso,
    const float* __restrict__ charge,   // [B, 256]
    float* __restrict__ out,            // [B*4096 iso][B*4096 aniso]
    int B)
{
    const int b   = blockIdx.x;
    const int tid = threadIdx.x;

    const f4* ci = (const f4*)(c_iso   + (size_t)b * HALF_N);
    const f4* ca = (const f4*)(c_aniso + (size_t)b * HALF_N);
    const f4* qi = (const f4*)(q_iso   + (size_t)b * HALF_N);
    const f4* qa = (const f4*)(q_aniso + (size_t)b * HALF_N);

    // Each thread: 2 float4 from each half of each array (coalesced,
    // lane-contiguous 16B accesses at float4 index j*512 + tid).
    f4 cv[4], qv[4];
#pragma unroll
    for (int j = 0; j < 2; ++j) {
        cv[j]     = ci[j * BLOCK + tid];
        qv[j]     = qi[j * BLOCK + tid];
        cv[j + 2] = ca[j * BLOCK + tid];
        qv[j + 2] = qa[j * BLOCK + tid];
    }

    float qc = 0.0f, qq = 0.0f;
#pragma unroll
    for (int j = 0; j < 4; ++j) {
        qc += qv[j][0] * cv[j][0] + qv[j][1] * cv[j][1]
            + qv[j][2] * cv[j][2] + qv[j][3] * cv[j][3];
        qq += qv[j][0] * qv[j][0] + qv[j][1] * qv[j][1]
            + qv[j][2] * qv[j][2] + qv[j][3] * qv[j][3];
    }

    // Pin the payload in VGPRs: the allocator may not rematerialize these
    // values by re-loading from global in the epilogue.
#pragma unroll
    for (int j = 0; j < 4; ++j) {
        asm volatile("" : "+v"(cv[j]), "+v"(qv[j]));
    }

    // charge: 256 elements per row; threads 256..511 contribute 0
    float Qp = (tid < 256) ? charge[(size_t)b * 256 + tid] : 0.0f;

    // wave-64 down-shuffle reduce
#pragma unroll
    for (int off = 32; off > 0; off >>= 1) {
        qc += __shfl_down(qc, off, 64);
        qq += __shfl_down(qq, off, 64);
        Qp += __shfl_down(Qp, off, 64);
    }

    __shared__ float s_qc[8], s_qq[8], s_Q[8];
    __shared__ float s_half_u;
    const int wave = tid >> 6;
    const int lane = tid & 63;
    if (lane == 0) { s_qc[wave] = qc; s_qq[wave] = qq; s_Q[wave] = Qp; }
    __syncthreads();
    if (tid == 0) {
        float tqc = 0.0f, tqq = 0.0f, tQ = 0.0f;
#pragma unroll
        for (int w = 0; w < 8; ++w) { tqc += s_qc[w]; tqq += s_qq[w]; tQ += s_Q[w]; }
        s_half_u = (tQ - tqc) / tqq;   // = u/2
    }
    __syncthreads();
    const float h = s_half_u;

    f4* oi = (f4*)(out + (size_t)b * HALF_N);
    f4* oa = (f4*)(out + (size_t)B * HALF_N + (size_t)b * HALF_N);
#pragma unroll
    for (int j = 0; j < 2; ++j) {
        f4 r = cv[j]     + h * qv[j];
        f4 s = cv[j + 2] + h * qv[j + 2];
        __builtin_nontemporal_store(r, &oi[j * BLOCK + tid]);
        __builtin_nontemporal_store(s, &oa[j * BLOCK + tid]);
    }
}

extern "C" void kernel_launch(void* const* d_in, const int* in_sizes, int n_in,
                              void* d_out, int out_size, void* d_ws, size_t ws_size,
                              hipStream_t stream) {
    const float* c_iso   = (const float*)d_in[0];
    const float* c_aniso = (const float*)d_in[1];
    const float* q_iso   = (const float*)d_in[2];
    const float* q_aniso = (const float*)d_in[3];
    const float* charge  = (const float*)d_in[4];
    float* out = (float*)d_out;

    const int B = in_sizes[0] / HALF_N;   // 4096

    qp_charge_norm_kernel<<<B, BLOCK, 0, stream>>>(
        c_iso, c_aniso, q_iso, q_aniso, charge, out, B);
}